// Round 1
// baseline (419.746 us; speedup 1.0000x reference)
//
#include <hip/hip_runtime.h>
#include <hip/hip_bf16.h>
#include <math.h>

typedef __attribute__((ext_vector_type(4))) float f32x4;
typedef __attribute__((ext_vector_type(8))) short bf16x8;
typedef __attribute__((ext_vector_type(4))) short s16x4;
typedef short s16;

#define S_LEN 2048
#define HIDN  2048
#define NH    32
#define NKVH  8
#define HD    64
#define KVW   512   // NKVH*HD

// round-to-nearest-even f32 -> bf16 (finite inputs)
__device__ __forceinline__ s16 f2bf(float f) {
  unsigned int u = __float_as_uint(f);
  unsigned int lsb = (u >> 16) & 1u;
  u += 0x7fffu + lsb;
  return (s16)(u >> 16);
}

__global__ __launch_bounds__(256) void cvt_kernel(const float* __restrict__ in,
                                                  s16* __restrict__ out, int n4) {
  int i = blockIdx.x * 256 + threadIdx.x;
  if (i < n4) {
    float4 f = reinterpret_cast<const float4*>(in)[i];
    s16x4 o;
    o.x = f2bf(f.x); o.y = f2bf(f.y); o.z = f2bf(f.z); o.w = f2bf(f.w);
    reinterpret_cast<s16x4*>(out)[i] = o;
  }
}

__device__ __forceinline__ void storeC(s16* C, size_t idx, float v)   { C[idx] = f2bf(v); }
__device__ __forceinline__ void storeC(float* C, size_t idx, float v) { C[idx] = v; }

// C[M,N] = A[M,K] * B[N,K]^T   (bf16 inputs, f32 accum)
// 128x128 tile, BK=32, 256 threads = 4 waves, each wave 64x64 (4x4 of 16x16x32)
template <typename OUT_T>
__global__ __launch_bounds__(256) void gemm_bt(const s16* __restrict__ A,
                                               const s16* __restrict__ B,
                                               OUT_T* __restrict__ C,
                                               int M, int N, int K) {
  __shared__ s16 As[128][40];
  __shared__ s16 Bs[128][40];

  const int t    = threadIdx.x;
  const int lane = t & 63;
  const int w    = t >> 6;
  const int wr   = (w >> 1) * 64;
  const int wc   = (w & 1) * 64;
  const int lr   = lane & 15;
  const int lk   = (lane >> 4) * 8;
  const int bm   = blockIdx.y * 128;
  const int bn   = blockIdx.x * 128;

  const int srow = t >> 2;
  const int sc8  = (t & 3) * 8;

  f32x4 acc[4][4];
#pragma unroll
  for (int m = 0; m < 4; ++m)
#pragma unroll
    for (int n = 0; n < 4; ++n)
      acc[m][n] = (f32x4){0.f, 0.f, 0.f, 0.f};

  for (int kt = 0; kt < K; kt += 32) {
#pragma unroll
    for (int p = 0; p < 2; ++p) {
      int row = srow + p * 64;
      *(bf16x8*)&As[row][sc8] = *(const bf16x8*)&A[(size_t)(bm + row) * K + kt + sc8];
      *(bf16x8*)&Bs[row][sc8] = *(const bf16x8*)&B[(size_t)(bn + row) * K + kt + sc8];
    }
    __syncthreads();

    bf16x8 af[4], bfr[4];
#pragma unroll
    for (int m = 0; m < 4; ++m) af[m]  = *(bf16x8*)&As[wr + m * 16 + lr][lk];
#pragma unroll
    for (int n = 0; n < 4; ++n) bfr[n] = *(bf16x8*)&Bs[wc + n * 16 + lr][lk];

#pragma unroll
    for (int m = 0; m < 4; ++m)
#pragma unroll
      for (int n = 0; n < 4; ++n)
        acc[m][n] = __builtin_amdgcn_mfma_f32_16x16x32_bf16(af[m], bfr[n], acc[m][n], 0, 0, 0);
    __syncthreads();
  }

#pragma unroll
  for (int m = 0; m < 4; ++m)
#pragma unroll
    for (int n = 0; n < 4; ++n) {
      int row = bm + wr + m * 16 + (lane >> 4) * 4;
      int col = bn + wc + n * 16 + lr;
#pragma unroll
      for (int j = 0; j < 4; ++j)
        storeC(C, (size_t)(row + j) * N + col, acc[m][n][j]);
    }
}

// Flash attention, causal, GQA. One block = one (head, 64 q-rows). 4 waves x 16 rows.
__global__ __launch_bounds__(256) void attn_kernel(const s16* __restrict__ Qb,  // [S][2048]
                                                   const s16* __restrict__ Kb,  // [S][512]
                                                   const s16* __restrict__ Vb,  // [S][512]
                                                   const int* __restrict__ am,  // [S]
                                                   s16* __restrict__ Ob) {      // [S][2048]
  __shared__ s16 Qs[64][72];
  __shared__ s16 Ks[32][72];
  __shared__ s16 Vts[64][40];    // [d][kv]
  __shared__ s16 Ps[4][16][40];  // per-wave P

  const int t    = threadIdx.x;
  const int lane = t & 63;
  const int w    = t >> 6;
  const int lr   = lane & 15;
  const int lg   = lane >> 4;
  const int lk   = lg * 8;

  const int qblk = blockIdx.x;
  const int h    = blockIdx.y;
  const int hk   = h >> 2;  // GQA group of 4
  const int q0   = qblk * 64;

  // stage Q (64x64)
#pragma unroll
  for (int p = 0; p < 2; ++p) {
    int c  = t + p * 256;
    int qr = c >> 3, qc8 = (c & 7) * 8;
    *(bf16x8*)&Qs[qr][qc8] = *(const bf16x8*)&Qb[(size_t)(q0 + qr) * HIDN + h * HD + qc8];
  }
  __syncthreads();

  bf16x8 qf0 = *(bf16x8*)&Qs[w * 16 + lr][lk];
  bf16x8 qf1 = *(bf16x8*)&Qs[w * 16 + lr][32 + lk];

  float m_i[4], l_i[4];
  f32x4 Oacc[4];
#pragma unroll
  for (int j = 0; j < 4; ++j) { m_i[j] = -INFINITY; l_i[j] = 0.f; }
#pragma unroll
  for (int nd = 0; nd < 4; ++nd) Oacc[nd] = (f32x4){0.f, 0.f, 0.f, 0.f};

  const int kr  = t >> 3;
  const int kc8 = (t & 7) * 8;

  for (int kv0 = 0; kv0 < q0 + 64; kv0 += 32) {
    __syncthreads();  // previous tile's MFMA reads done
    // stage K (32x64) and V transposed (64x32)
    *(bf16x8*)&Ks[kr][kc8] = *(const bf16x8*)&Kb[(size_t)(kv0 + kr) * KVW + hk * HD + kc8];
    bf16x8 vv = *(const bf16x8*)&Vb[(size_t)(kv0 + kr) * KVW + hk * HD + kc8];
#pragma unroll
    for (int i = 0; i < 8; ++i) Vts[kc8 + i][kr] = vv[i];
    __syncthreads();

    // S = Q K^T  (16 q-rows x 32 kv-cols per wave)
    f32x4 s0 = (f32x4){0.f, 0.f, 0.f, 0.f};
    f32x4 s1 = (f32x4){0.f, 0.f, 0.f, 0.f};
    {
      bf16x8 k00 = *(bf16x8*)&Ks[lr][lk];
      bf16x8 k01 = *(bf16x8*)&Ks[lr][32 + lk];
      bf16x8 k10 = *(bf16x8*)&Ks[16 + lr][lk];
      bf16x8 k11 = *(bf16x8*)&Ks[16 + lr][32 + lk];
      s0 = __builtin_amdgcn_mfma_f32_16x16x32_bf16(qf0, k00, s0, 0, 0, 0);
      s0 = __builtin_amdgcn_mfma_f32_16x16x32_bf16(qf1, k01, s0, 0, 0, 0);
      s1 = __builtin_amdgcn_mfma_f32_16x16x32_bf16(qf0, k10, s1, 0, 0, 0);
      s1 = __builtin_amdgcn_mfma_f32_16x16x32_bf16(qf1, k11, s1, 0, 0, 0);
    }

    float sc[2][4];
    const int qrow_base = q0 + w * 16 + lg * 4;
#pragma unroll
    for (int n = 0; n < 2; ++n) {
      int col = kv0 + n * 16 + lr;
      int amv = am[col];
      f32x4 sv = (n == 0) ? s0 : s1;
#pragma unroll
      for (int j = 0; j < 4; ++j) {
        bool ok = (col <= qrow_base + j) && (amv != 0);
        sc[n][j] = ok ? sv[j] * 0.125f : -INFINITY;
      }
    }

#pragma unroll
    for (int j = 0; j < 4; ++j) {
      float rmax = fmaxf(sc[0][j], sc[1][j]);
#pragma unroll
      for (int off = 1; off < 16; off <<= 1)
        rmax = fmaxf(rmax, __shfl_xor(rmax, off));

      float nm = fmaxf(m_i[j], rmax);
      float al = (nm == -INFINITY) ? 1.f : __expf(m_i[j] - nm);
      float p0 = (nm == -INFINITY) ? 0.f : __expf(sc[0][j] - nm);
      float p1 = (nm == -INFINITY) ? 0.f : __expf(sc[1][j] - nm);

      float rs = p0 + p1;
#pragma unroll
      for (int off = 1; off < 16; off <<= 1)
        rs += __shfl_xor(rs, off);

      l_i[j] = l_i[j] * al + rs;
      m_i[j] = nm;

      Ps[w][lg * 4 + j][lr]      = f2bf(p0);
      Ps[w][lg * 4 + j][16 + lr] = f2bf(p1);

#pragma unroll
      for (int nd = 0; nd < 4; ++nd) Oacc[nd][j] *= al;
    }

    // O += P V
    bf16x8 pf = *(bf16x8*)&Ps[w][lr][lk];
#pragma unroll
    for (int nd = 0; nd < 4; ++nd) {
      bf16x8 vf = *(bf16x8*)&Vts[nd * 16 + lr][lk];
      Oacc[nd] = __builtin_amdgcn_mfma_f32_16x16x32_bf16(pf, vf, Oacc[nd], 0, 0, 0);
    }
  }

#pragma unroll
  for (int nd = 0; nd < 4; ++nd)
#pragma unroll
    for (int j = 0; j < 4; ++j) {
      int row = q0 + w * 16 + lg * 4 + j;
      int col = h * HD + nd * 16 + lr;
      Ob[(size_t)row * HIDN + col] = f2bf(Oacc[nd][j] / l_i[j]);
    }
}

extern "C" void kernel_launch(void* const* d_in, const int* in_sizes, int n_in,
                              void* d_out, int out_size, void* d_ws, size_t ws_size,
                              hipStream_t stream) {
  const float* hidden = (const float*)d_in[0];
  const int*   am     = (const int*)d_in[1];
  const float* Wq     = (const float*)d_in[2];
  const float* Wk     = (const float*)d_in[3];
  const float* Wv     = (const float*)d_in[4];
  const float* Wo     = (const float*)d_in[5];
  float* out = (float*)d_out;

  // workspace layout (bf16 elements); total 48 MB
  s16* hb  = (s16*)d_ws;            // hidden     [2048][2048]
  s16* wqb = hb  + 4194304;         // Wq         [2048][2048]
  s16* wkb = wqb + 4194304;         // Wk         [512][2048]
  s16* wvb = wkb + 1048576;         // Wv         [512][2048]
  s16* wob = wvb + 1048576;         // Wo         [2048][2048]
  s16* Qb  = wob + 4194304;         // Q          [2048][2048]
  s16* Kb  = Qb  + 4194304;         // K          [2048][512]
  s16* Vb  = Kb  + 1048576;         // V          [2048][512]
  s16* Ab  = Vb  + 1048576;         // attn out   [2048][2048]

  cvt_kernel<<<4096, 256, 0, stream>>>(hidden, hb, 1048576);
  cvt_kernel<<<4096, 256, 0, stream>>>(Wq, wqb, 1048576);
  cvt_kernel<<<1024, 256, 0, stream>>>(Wk, wkb, 262144);
  cvt_kernel<<<1024, 256, 0, stream>>>(Wv, wvb, 262144);
  cvt_kernel<<<4096, 256, 0, stream>>>(Wo, wob, 1048576);

  gemm_bt<s16><<<dim3(16, 16), 256, 0, stream>>>(hb, wqb, Qb, 2048, 2048, 2048);
  gemm_bt<s16><<<dim3(4, 16), 256, 0, stream>>>(hb, wkb, Kb, 2048, 512, 2048);
  gemm_bt<s16><<<dim3(4, 16), 256, 0, stream>>>(hb, wvb, Vb, 2048, 512, 2048);

  attn_kernel<<<dim3(32, 32), 256, 0, stream>>>(Qb, Kb, Vb, am, Ab);

  gemm_bt<float><<<dim3(16, 16), 256, 0, stream>>>(Ab, wob, out, 2048, 2048, 2048);
}

// Round 2
// 252.048 us; speedup vs baseline: 1.6653x; 1.6653x over previous
//
#include <hip/hip_runtime.h>
#include <hip/hip_bf16.h>
#include <math.h>

typedef __attribute__((ext_vector_type(4))) float f32x4;
typedef __attribute__((ext_vector_type(8))) short bf16x8;
typedef __attribute__((ext_vector_type(4))) short s16x4;
typedef short s16;

#define S_LEN 2048
#define HIDN  2048
#define QKVW  3072   // fused QKV row width
#define NH    32
#define NKVH  8
#define HD    64

// round-to-nearest-even f32 -> bf16 (finite inputs)
__device__ __forceinline__ s16 f2bf(float f) {
  unsigned int u = __float_as_uint(f);
  unsigned int lsb = (u >> 16) & 1u;
  u += 0x7fffu + lsb;
  return (s16)(u >> 16);
}

__device__ __forceinline__ void gload16(const void* g, void* l) {
  __builtin_amdgcn_global_load_lds(
      (const __attribute__((address_space(1))) void*)g,
      (__attribute__((address_space(3))) void*)l, 16, 0, 0);
}

__global__ __launch_bounds__(256) void cvt_kernel(const float* __restrict__ in,
                                                  s16* __restrict__ out, int n4) {
  int i = blockIdx.x * 256 + threadIdx.x;
  if (i < n4) {
    float4 f = reinterpret_cast<const float4*>(in)[i];
    s16x4 o;
    o.x = f2bf(f.x); o.y = f2bf(f.y); o.z = f2bf(f.z); o.w = f2bf(f.w);
    reinterpret_cast<s16x4*>(out)[i] = o;
  }
}

__device__ __forceinline__ void storeC(s16* C, size_t idx, float v)   { C[idx] = f2bf(v); }
__device__ __forceinline__ void storeC(float* C, size_t idx, float v) { C[idx] = v; }

// C[M,N] = A[M,K] * B[N,K]^T  (bf16 in, f32 accum). BM=128, BN=64, BK=32.
// 4 waves in 2x2; each wave 64x32 (4x2 frags of 16x16x32).
template <typename OUT_T>
__global__ __launch_bounds__(256) void gemm_bt(const s16* __restrict__ A,
                                               const s16* __restrict__ B,
                                               OUT_T* __restrict__ C,
                                               int M, int N, int K) {
  __shared__ s16 As[128][40];
  __shared__ s16 Bs[64][40];

  const int t    = threadIdx.x;
  const int lane = t & 63;
  const int w    = t >> 6;
  const int wr   = (w >> 1) * 64;
  const int wc   = (w & 1) * 32;
  const int lr   = lane & 15;
  const int lg   = lane >> 4;
  const int lk   = lg * 8;
  const int bm   = blockIdx.y * 128;
  const int bn   = blockIdx.x * 64;

  const int arow = t >> 2;          // A stage: 2 chunks (rows t>>2, t>>2+64)
  const int ac8  = (t & 3) * 8;

  f32x4 acc[4][2];
#pragma unroll
  for (int m = 0; m < 4; ++m)
#pragma unroll
    for (int n = 0; n < 2; ++n)
      acc[m][n] = (f32x4){0.f, 0.f, 0.f, 0.f};

  for (int kt = 0; kt < K; kt += 32) {
    *(bf16x8*)&As[arow][ac8]      = *(const bf16x8*)&A[(size_t)(bm + arow) * K + kt + ac8];
    *(bf16x8*)&As[arow + 64][ac8] = *(const bf16x8*)&A[(size_t)(bm + arow + 64) * K + kt + ac8];
    *(bf16x8*)&Bs[arow][ac8]      = *(const bf16x8*)&B[(size_t)(bn + arow) * K + kt + ac8];
    __syncthreads();

    bf16x8 af[4], bfr[2];
#pragma unroll
    for (int m = 0; m < 4; ++m) af[m]  = *(bf16x8*)&As[wr + m * 16 + lr][lk];
#pragma unroll
    for (int n = 0; n < 2; ++n) bfr[n] = *(bf16x8*)&Bs[wc + n * 16 + lr][lk];

#pragma unroll
    for (int m = 0; m < 4; ++m)
#pragma unroll
      for (int n = 0; n < 2; ++n)
        acc[m][n] = __builtin_amdgcn_mfma_f32_16x16x32_bf16(af[m], bfr[n], acc[m][n], 0, 0, 0);
    __syncthreads();
  }

#pragma unroll
  for (int m = 0; m < 4; ++m)
#pragma unroll
    for (int n = 0; n < 2; ++n) {
      int row = bm + wr + m * 16 + lg * 4;
      int col = bn + wc + n * 16 + lr;
#pragma unroll
      for (int j = 0; j < 4; ++j)
        storeC(C, (size_t)(row + j) * N + col, acc[m][n][j]);
    }
}

// ---------------- flash attention ----------------
// Block = (head, 64 q-rows), 4 waves, wave = 16 q-rows. KVBLK = 64.
// K: linear LDS, staged by global_load_lds with pre-swizzled source cols.
// V: transposed into XOR-swizzled byte layout.
__device__ __forceinline__ int swz7(int row) { return (row ^ (row >> 3)) & 7; }

__global__ __launch_bounds__(256) void attn_kernel(
    const s16* __restrict__ QKV,   // [2048][3072]
    const int* __restrict__ am,    // [2048]
    s16* __restrict__ Ob) {        // [2048][2048]
  __shared__ alignas(16) char KsB[8192];        // K tile [64 kv][64 d], swizzled slots
  __shared__ alignas(16) char VsB[8192];        // V^T    [64 d][64 kv], swizzled slots
  __shared__ alignas(16) s16 Ps[4][16][72];     // per-wave P [16 q][64 kv], padded

  const int t    = threadIdx.x;
  const int lane = t & 63;
  const int w    = t >> 6;
  const int lr   = lane & 15;
  const int lg   = lane >> 4;

  const int qblk = (int)gridDim.x - 1 - (int)blockIdx.x;
  const int h    = blockIdx.y;
  const int hk   = h >> 2;
  const int q0   = qblk * 64;
  const int kbase = 2048 + hk * 64;
  const int vbase = 2560 + hk * 64;

  const int qrow = q0 + w * 16 + lr;
  bf16x8 qf0 = *(const bf16x8*)&QKV[(size_t)qrow * QKVW + h * 64 + lg * 8];
  bf16x8 qf1 = *(const bf16x8*)&QKV[(size_t)qrow * QKVW + h * 64 + 32 + lg * 8];

  float m_i[4], l_i[4];
  f32x4 Oacc[4];
#pragma unroll
  for (int j = 0; j < 4; ++j) { m_i[j] = -1e30f; l_i[j] = 0.f; }
#pragma unroll
  for (int nd = 0; nd < 4; ++nd) Oacc[nd] = (f32x4){0.f, 0.f, 0.f, 0.f};

  const float CF = 0.18033688f;  // 0.125 * log2(e)
  const int nt = qblk + 1;

  for (int it = 0; it < nt; ++it) {
    const int kv0 = it * 64;
    __syncthreads();  // previous tile fully consumed

    // --- stage K: global_load_lds, source slot pre-swizzled ---
#pragma unroll
    for (int p = 0; p < 2; ++p) {
      int c    = w * 2 + p;                 // 1KB chunk, wave-uniform
      int row  = c * 8 + (lane >> 3);
      int slot = (lane & 7) ^ swz7(row);
      gload16(&QKV[(size_t)(kv0 + row) * QKVW + kbase + slot * 8], KsB + c * 1024);
    }
    // --- stage V transposed, swizzled scalar stores ---
#pragma unroll
    for (int p = 0; p < 2; ++p) {
      int c2  = t + p * 256;
      int rv  = c2 >> 3;            // kv
      int cv8 = (c2 & 7) * 8;       // d start
      bf16x8 vv = *(const bf16x8*)&QKV[(size_t)(kv0 + rv) * QKVW + vbase + cv8];
#pragma unroll
      for (int i = 0; i < 8; ++i) {
        int d = cv8 + i;
        *(s16*)&VsB[(d * 128 + rv * 2) ^ (swz7(d) << 4)] = vv[i];
      }
    }
    __syncthreads();

    // --- S = Q K^T ---
    f32x4 s[4];
#pragma unroll
    for (int n = 0; n < 4; ++n) {
      int row = n * 16 + lr;
      int sw  = swz7(row) << 4;
      bf16x8 k0 = *(bf16x8*)&KsB[(row * 128 + lg * 16) ^ sw];
      bf16x8 k1 = *(bf16x8*)&KsB[(row * 128 + 64 + lg * 16) ^ sw];
      f32x4 z = (f32x4){0.f, 0.f, 0.f, 0.f};
      z = __builtin_amdgcn_mfma_f32_16x16x32_bf16(qf0, k0, z, 0, 0, 0);
      s[n] = __builtin_amdgcn_mfma_f32_16x16x32_bf16(qf1, k1, z, 0, 0, 0);
    }

    // scale into log2 domain
    f32x4 tv[4];
#pragma unroll
    for (int n = 0; n < 4; ++n)
#pragma unroll
      for (int j = 0; j < 4; ++j) tv[n][j] = s[n][j] * CF;

    // masking (skipped for interior tiles with full attention mask)
    int a0 = am[kv0 + lr], a1 = am[kv0 + 16 + lr], a2 = am[kv0 + 32 + lr], a3 = am[kv0 + 48 + lr];
    bool allam = a0 && a1 && a2 && a3;
    bool need  = (kv0 + 63 > q0 + 16 * w) || (__ballot(allam) != ~0ull);
    if (need) {
      int rowq = q0 + 16 * w + 4 * lg;
      int amv[4] = {a0, a1, a2, a3};
#pragma unroll
      for (int n = 0; n < 4; ++n) {
        int col = kv0 + 16 * n + lr;
#pragma unroll
        for (int j = 0; j < 4; ++j)
          if (col > rowq + j || !amv[n]) tv[n][j] = -INFINITY;
      }
    }

    // online softmax (rows spread over 16 lanes in lg-group)
#pragma unroll
    for (int j = 0; j < 4; ++j) {
      float rmax = fmaxf(fmaxf(tv[0][j], tv[1][j]), fmaxf(tv[2][j], tv[3][j]));
#pragma unroll
      for (int off = 1; off < 16; off <<= 1) rmax = fmaxf(rmax, __shfl_xor(rmax, off));
      float nm = fmaxf(m_i[j], rmax);
      float al = __builtin_amdgcn_exp2f(m_i[j] - nm);
      float p0 = __builtin_amdgcn_exp2f(tv[0][j] - nm);
      float p1 = __builtin_amdgcn_exp2f(tv[1][j] - nm);
      float p2 = __builtin_amdgcn_exp2f(tv[2][j] - nm);
      float p3 = __builtin_amdgcn_exp2f(tv[3][j] - nm);
      float rs = (p0 + p1) + (p2 + p3);
#pragma unroll
      for (int off = 1; off < 16; off <<= 1) rs += __shfl_xor(rs, off);
      m_i[j] = nm;
      l_i[j] = l_i[j] * al + rs;
      int qr = 4 * lg + j;
      Ps[w][qr][lr]      = f2bf(p0);
      Ps[w][qr][16 + lr] = f2bf(p1);
      Ps[w][qr][32 + lr] = f2bf(p2);
      Ps[w][qr][48 + lr] = f2bf(p3);
#pragma unroll
      for (int nd = 0; nd < 4; ++nd) Oacc[nd][j] *= al;
    }

    // --- O += P V ---
    bf16x8 pf0 = *(bf16x8*)&Ps[w][lr][lg * 8];
    bf16x8 pf1 = *(bf16x8*)&Ps[w][lr][32 + lg * 8];
#pragma unroll
    for (int nd = 0; nd < 4; ++nd) {
      int d  = nd * 16 + lr;
      int sw = swz7(d) << 4;
      bf16x8 v0 = *(bf16x8*)&VsB[(d * 128 + lg * 16) ^ sw];
      bf16x8 v1 = *(bf16x8*)&VsB[(d * 128 + 64 + lg * 16) ^ sw];
      Oacc[nd] = __builtin_amdgcn_mfma_f32_16x16x32_bf16(pf0, v0, Oacc[nd], 0, 0, 0);
      Oacc[nd] = __builtin_amdgcn_mfma_f32_16x16x32_bf16(pf1, v1, Oacc[nd], 0, 0, 0);
    }
  }

  float inv[4];
#pragma unroll
  for (int j = 0; j < 4; ++j) inv[j] = 1.0f / l_i[j];
#pragma unroll
  for (int nd = 0; nd < 4; ++nd)
#pragma unroll
    for (int j = 0; j < 4; ++j) {
      int row = q0 + 16 * w + 4 * lg + j;
      int col = h * 64 + nd * 16 + lr;
      Ob[(size_t)row * HIDN + col] = f2bf(Oacc[nd][j] * inv[j]);
    }
}

extern "C" void kernel_launch(void* const* d_in, const int* in_sizes, int n_in,
                              void* d_out, int out_size, void* d_ws, size_t ws_size,
                              hipStream_t stream) {
  const float* hidden = (const float*)d_in[0];
  const int*   am     = (const int*)d_in[1];
  const float* Wq     = (const float*)d_in[2];
  const float* Wk     = (const float*)d_in[3];
  const float* Wv     = (const float*)d_in[4];
  const float* Wo     = (const float*)d_in[5];
  float* out = (float*)d_out;

  // workspace (bf16 elements), ~50.3 MB total
  s16* hb    = (s16*)d_ws;          // hidden  [2048][2048]
  s16* wqkvb = hb    + 4194304;     // W_qkv   [3072][2048]
  s16* wob   = wqkvb + 6291456;     // Wo      [2048][2048]
  s16* QKVb  = wob   + 4194304;     // QKV     [2048][3072]
  s16* Ab    = QKVb  + 6291456;     // attnout [2048][2048]

  cvt_kernel<<<4096, 256, 0, stream>>>(hidden, hb, 1048576);
  cvt_kernel<<<4096, 256, 0, stream>>>(Wq, wqkvb, 1048576);
  cvt_kernel<<<1024, 256, 0, stream>>>(Wk, wqkvb + 4194304, 262144);
  cvt_kernel<<<1024, 256, 0, stream>>>(Wv, wqkvb + 5242880, 262144);
  cvt_kernel<<<4096, 256, 0, stream>>>(Wo, wob, 1048576);

  gemm_bt<s16><<<dim3(48, 16), 256, 0, stream>>>(hb, wqkvb, QKVb, 2048, 3072, 2048);

  attn_kernel<<<dim3(32, 32), 256, 0, stream>>>(QKVb, am, Ab);

  gemm_bt<float><<<dim3(32, 16), 256, 0, stream>>>(Ab, wob, out, 2048, 2048, 2048);
}

// Round 3
// 208.286 us; speedup vs baseline: 2.0152x; 1.2101x over previous
//
#include <hip/hip_runtime.h>
#include <hip/hip_bf16.h>
#include <math.h>

typedef __attribute__((ext_vector_type(4))) float f32x4;
typedef __attribute__((ext_vector_type(8))) short bf16x8;
typedef __attribute__((ext_vector_type(4))) short s16x4;
typedef short s16;
typedef unsigned int u32;
typedef unsigned short u16;

#define S_LEN 2048
#define HIDN  2048
#define QKVW  3072
#define NH    32
#define NKVH  8
#define HD    64

__device__ __forceinline__ s16 f2bf(float f) {
  unsigned int u = __float_as_uint(f);
  unsigned int lsb = (u >> 16) & 1u;
  u += 0x7fffu + lsb;
  return (s16)(u >> 16);
}

__device__ __forceinline__ void gload16(const void* g, void* l) {
  __builtin_amdgcn_global_load_lds(
      (const __attribute__((address_space(1))) void*)g,
      (__attribute__((address_space(3))) void*)l, 16, 0, 0);
}

__global__ __launch_bounds__(256) void cvt_kernel(const float* __restrict__ in,
                                                  s16* __restrict__ out, int n4) {
  int i = blockIdx.x * 256 + threadIdx.x;
  if (i < n4) {
    float4 f = reinterpret_cast<const float4*>(in)[i];
    s16x4 o;
    o.x = f2bf(f.x); o.y = f2bf(f.y); o.z = f2bf(f.z); o.w = f2bf(f.w);
    reinterpret_cast<s16x4*>(out)[i] = o;
  }
}

__device__ __forceinline__ void storeC(s16* C, size_t idx, float v)   { C[idx] = f2bf(v); }
__device__ __forceinline__ void storeC(float* C, size_t idx, float v) { C[idx] = v; }

// C[M,N] = A[M,K] * B[N,K]^T. BM=128, BN=64, BK=32. global_load_lds staging.
template <typename OUT_T>
__global__ __launch_bounds__(256) void gemm_bt(const s16* __restrict__ A,
                                               const s16* __restrict__ B,
                                               OUT_T* __restrict__ C,
                                               int M, int N, int K) {
  __shared__ alignas(16) s16 As[128 * 32];
  __shared__ alignas(16) s16 Bs[64 * 32];

  const int t    = threadIdx.x;
  const int lane = t & 63;
  const int w    = t >> 6;
  const int wr   = (w >> 1) * 64;
  const int wc   = (w & 1) * 32;
  const int lr   = lane & 15;
  const int lg   = lane >> 4;
  const int bm   = blockIdx.y * 128;
  const int bn   = blockIdx.x * 64;

  const int crow = lane >> 2;        // 0..15
  const int cc8  = (lane & 3) * 8;   // 0,8,16,24

  f32x4 acc[4][2];
#pragma unroll
  for (int m = 0; m < 4; ++m)
#pragma unroll
    for (int n = 0; n < 2; ++n)
      acc[m][n] = (f32x4){0.f, 0.f, 0.f, 0.f};

  for (int kt = 0; kt < K; kt += 32) {
    // A: 8 x 1KB chunks, wave w does chunks {2w, 2w+1}; B: chunk w
#pragma unroll
    for (int p = 0; p < 2; ++p) {
      int c = w * 2 + p;
      gload16(&A[(size_t)(bm + c * 16 + crow) * K + kt + cc8], (char*)As + c * 1024);
    }
    gload16(&B[(size_t)(bn + w * 16 + crow) * K + kt + cc8], (char*)Bs + w * 1024);
    __syncthreads();  // drains vmcnt -> LDS ready

    bf16x8 af[4], bfr[2];
#pragma unroll
    for (int m = 0; m < 4; ++m) af[m]  = *(bf16x8*)&As[(wr + m * 16 + lr) * 32 + lg * 8];
#pragma unroll
    for (int n = 0; n < 2; ++n) bfr[n] = *(bf16x8*)&Bs[(wc + n * 16 + lr) * 32 + lg * 8];

#pragma unroll
    for (int m = 0; m < 4; ++m)
#pragma unroll
      for (int n = 0; n < 2; ++n)
        acc[m][n] = __builtin_amdgcn_mfma_f32_16x16x32_bf16(af[m], bfr[n], acc[m][n], 0, 0, 0);
    __syncthreads();
  }

#pragma unroll
  for (int m = 0; m < 4; ++m)
#pragma unroll
    for (int n = 0; n < 2; ++n) {
      int row = bm + wr + m * 16 + lg * 4;
      int col = bn + wc + n * 16 + lr;
#pragma unroll
      for (int j = 0; j < 4; ++j)
        storeC(C, (size_t)(row + j) * N + col, acc[m][n][j]);
    }
}

// ---------------- flash attention (swapped-QK, in-register softmax) ----------
__device__ __forceinline__ int swz7(int row) { return (row ^ (row >> 3)) & 7; }

__global__ __launch_bounds__(256) void attn_kernel(
    const s16* __restrict__ QKV,   // [2048][3072]
    const int* __restrict__ am,    // [2048]
    s16* __restrict__ Ob) {        // [2048][2048]
  __shared__ alignas(16) char KsB[2][8192];   // K [64 kv][64 d], swizzled slots
  __shared__ alignas(16) char VsB[2][8192];   // V^T [64 d][64 kv], swizzled
  __shared__ alignas(16) s16 Ps[4][16][72];   // per-wave P [16 q][64 kv]

  const int t    = threadIdx.x;
  const int lane = t & 63;
  const int w    = t >> 6;
  const int lr   = lane & 15;
  const int lg   = lane >> 4;

  const int qblk = (int)gridDim.x - 1 - (int)blockIdx.x;
  const int h    = blockIdx.y;
  const int hk   = h >> 2;
  const int q0   = qblk * 64;
  const int kbase = 2048 + hk * 64;
  const int vbase = 2560 + hk * 64;

  const int qrow = q0 + w * 16 + lr;
  bf16x8 qf0 = *(const bf16x8*)&QKV[(size_t)qrow * QKVW + h * 64 + lg * 8];
  bf16x8 qf1 = *(const bf16x8*)&QKV[(size_t)qrow * QKVW + h * 64 + 32 + lg * 8];

  float m_i = -1e30f, l_i = 0.f;
  f32x4 Oacc[4];
#pragma unroll
  for (int nd = 0; nd < 4; ++nd) Oacc[nd] = (f32x4){0.f, 0.f, 0.f, 0.f};

  const float CF = 0.18033688f;  // 0.125 * log2(e)
  const int nt = qblk + 1;

  // staging index precompute
  const int krow  = lane >> 3;            // K chunk sub-row
  const int kslotb= lane & 7;
  const int vkv   = 2 * (t >> 3);         // V: kv pair
  const int vd8   = (t & 7) * 8;          // V: d block

  // ---- prologue: stage tile 0 into buffer 0 ----
  {
#pragma unroll
    for (int p = 0; p < 2; ++p) {
      int c   = w * 2 + p;
      int row = c * 8 + krow;
      int slot = kslotb ^ swz7(row);
      gload16(&QKV[(size_t)row * QKVW + kbase + slot * 8], KsB[0] + c * 1024);
    }
    bf16x8 va = *(const bf16x8*)&QKV[(size_t)vkv * QKVW + vbase + vd8];
    bf16x8 vb = *(const bf16x8*)&QKV[(size_t)(vkv + 1) * QKVW + vbase + vd8];
#pragma unroll
    for (int i = 0; i < 8; ++i) {
      int d = vd8 + i;
      u32 pk = (u32)(u16)va[i] | ((u32)(u16)vb[i] << 16);
      *(u32*)&VsB[0][(d * 128 + vkv * 2) ^ (swz7(d) << 4)] = pk;
    }
    __syncthreads();
  }

  for (int it = 0; it < nt; ++it) {
    const int cur = it & 1;
    const int kv0 = it * 64;

    // ---- async stage of next tile (issue early) ----
    bf16x8 va, vb;
    const bool pre = (it + 1 < nt);
    if (pre) {
      const int nk0 = kv0 + 64;
#pragma unroll
      for (int p = 0; p < 2; ++p) {
        int c   = w * 2 + p;
        int row = c * 8 + krow;
        int slot = kslotb ^ swz7(row);
        gload16(&QKV[(size_t)(nk0 + row) * QKVW + kbase + slot * 8], KsB[cur ^ 1] + c * 1024);
      }
      va = *(const bf16x8*)&QKV[(size_t)(nk0 + vkv) * QKVW + vbase + vd8];
      vb = *(const bf16x8*)&QKV[(size_t)(nk0 + vkv + 1) * QKVW + vbase + vd8];
    }

    // ---- S^T = K Q^T : lane holds q = lr, kv = kv0 + 16n + 4lg + j ----
    f32x4 sn[4];
#pragma unroll
    for (int n = 0; n < 4; ++n) {
      int row = n * 16 + lr;
      int sw  = swz7(row) << 4;
      bf16x8 k0 = *(bf16x8*)&KsB[cur][(row * 128 + lg * 16) ^ sw];
      bf16x8 k1 = *(bf16x8*)&KsB[cur][(row * 128 + 64 + lg * 16) ^ sw];
      f32x4 z = (f32x4){0.f, 0.f, 0.f, 0.f};
      z = __builtin_amdgcn_mfma_f32_16x16x32_bf16(k0, qf0, z, 0, 0, 0);
      sn[n] = __builtin_amdgcn_mfma_f32_16x16x32_bf16(k1, qf1, z, 0, 0, 0);
    }

    // ---- mask + scale ----
    float pv[16];
    int a = am[kv0 + lane];
    unsigned long long m64 = __ballot(a != 0);
    bool interior = (kv0 + 63 <= q0 + 16 * w) && (m64 == ~0ull);
    if (interior) {
#pragma unroll
      for (int n = 0; n < 4; ++n)
#pragma unroll
        for (int j = 0; j < 4; ++j) pv[n * 4 + j] = sn[n][j] * CF;
    } else {
      const int qg = q0 + 16 * w + lr;
#pragma unroll
      for (int n = 0; n < 4; ++n) {
        u32 un = (u32)(m64 >> (16 * n + 4 * lg)) & 0xFu;
#pragma unroll
        for (int j = 0; j < 4; ++j) {
          int kvg = kv0 + 16 * n + 4 * lg + j;
          bool ok = (kvg <= qg) && ((un >> j) & 1u);
          pv[n * 4 + j] = ok ? sn[n][j] * CF : -INFINITY;
        }
      }
    }

    // ---- in-register online softmax (per lane: one q row piece) ----
    float lmax = pv[0];
#pragma unroll
    for (int i = 1; i < 16; ++i) lmax = fmaxf(lmax, pv[i]);
    lmax = fmaxf(lmax, __shfl_xor(lmax, 16));
    lmax = fmaxf(lmax, __shfl_xor(lmax, 32));

    float nm = fmaxf(m_i, lmax);
    float al = __builtin_amdgcn_exp2f(m_i - nm);
    m_i = nm;

    float lsum = 0.f;
#pragma unroll
    for (int n = 0; n < 4; ++n)
#pragma unroll
      for (int j = 0; j < 4; ++j) {
        float p = __builtin_amdgcn_exp2f(pv[n * 4 + j] - nm);
        Ps[w][lr][16 * n + 4 * lg + j] = f2bf(p);
        lsum += p;
      }
    lsum += __shfl_xor(lsum, 16);
    lsum += __shfl_xor(lsum, 32);
    l_i = l_i * al + lsum;

    // broadcast al to the C-layout rows (q = 4*lg + j), rescale O
    float albc[4];
#pragma unroll
    for (int j = 0; j < 4; ++j) albc[j] = __shfl(al, 20 * lg + j);
#pragma unroll
    for (int nd = 0; nd < 4; ++nd)
#pragma unroll
      for (int j = 0; j < 4; ++j) Oacc[nd][j] *= albc[j];

    // ---- O += P V ----
    bf16x8 pf0 = *(bf16x8*)&Ps[w][lr][lg * 8];
    bf16x8 pf1 = *(bf16x8*)&Ps[w][lr][32 + lg * 8];
#pragma unroll
    for (int nd = 0; nd < 4; ++nd) {
      int d  = nd * 16 + lr;
      int sw = swz7(d) << 4;
      bf16x8 v0 = *(bf16x8*)&VsB[cur][(d * 128 + lg * 16) ^ sw];
      bf16x8 v1 = *(bf16x8*)&VsB[cur][(d * 128 + 64 + lg * 16) ^ sw];
      Oacc[nd] = __builtin_amdgcn_mfma_f32_16x16x32_bf16(pf0, v0, Oacc[nd], 0, 0, 0);
      Oacc[nd] = __builtin_amdgcn_mfma_f32_16x16x32_bf16(pf1, v1, Oacc[nd], 0, 0, 0);
    }

    // ---- late half of async stage: pack + write V^T(next) ----
    if (pre) {
#pragma unroll
      for (int i = 0; i < 8; ++i) {
        int d = vd8 + i;
        u32 pk = (u32)(u16)va[i] | ((u32)(u16)vb[i] << 16);
        *(u32*)&VsB[cur ^ 1][(d * 128 + vkv * 2) ^ (swz7(d) << 4)] = pk;
      }
    }
    __syncthreads();  // drains K gload vmcnt + V ds_writes for all waves
  }

  // epilogue
  float linv[4];
#pragma unroll
  for (int j = 0; j < 4; ++j) linv[j] = 1.0f / __shfl(l_i, 20 * lg + j);
#pragma unroll
  for (int nd = 0; nd < 4; ++nd)
#pragma unroll
    for (int j = 0; j < 4; ++j) {
      int row = q0 + 16 * w + 4 * lg + j;
      int col = h * 64 + nd * 16 + lr;
      Ob[(size_t)row * HIDN + col] = f2bf(Oacc[nd][j] * linv[j]);
    }
}

extern "C" void kernel_launch(void* const* d_in, const int* in_sizes, int n_in,
                              void* d_out, int out_size, void* d_ws, size_t ws_size,
                              hipStream_t stream) {
  const float* hidden = (const float*)d_in[0];
  const int*   am     = (const int*)d_in[1];
  const float* Wq     = (const float*)d_in[2];
  const float* Wk     = (const float*)d_in[3];
  const float* Wv     = (const float*)d_in[4];
  const float* Wo     = (const float*)d_in[5];
  float* out = (float*)d_out;

  s16* hb    = (s16*)d_ws;          // hidden  [2048][2048]
  s16* wqkvb = hb    + 4194304;     // W_qkv   [3072][2048]
  s16* wob   = wqkvb + 6291456;     // Wo      [2048][2048]
  s16* QKVb  = wob   + 4194304;     // QKV     [2048][3072]
  s16* Ab    = QKVb  + 6291456;     // attnout [2048][2048]

  cvt_kernel<<<4096, 256, 0, stream>>>(hidden, hb, 1048576);
  cvt_kernel<<<4096, 256, 0, stream>>>(Wq, wqkvb, 1048576);
  cvt_kernel<<<1024, 256, 0, stream>>>(Wk, wqkvb + 4194304, 262144);
  cvt_kernel<<<1024, 256, 0, stream>>>(Wv, wqkvb + 5242880, 262144);
  cvt_kernel<<<4096, 256, 0, stream>>>(Wo, wob, 1048576);

  gemm_bt<s16><<<dim3(48, 16), 256, 0, stream>>>(hb, wqkvb, QKVb, 2048, 3072, 2048);

  attn_kernel<<<dim3(32, 32), 256, 0, stream>>>(QKVb, am, Ab);

  gemm_bt<float><<<dim3(32, 16), 256, 0, stream>>>(Ab, wob, out, 2048, 2048, 2048);
}

// Round 4
// 207.058 us; speedup vs baseline: 2.0272x; 1.0059x over previous
//
#include <hip/hip_runtime.h>
#include <hip/hip_bf16.h>
#include <math.h>

typedef __attribute__((ext_vector_type(4))) float f32x4;
typedef __attribute__((ext_vector_type(8))) short bf16x8;
typedef __attribute__((ext_vector_type(4))) short s16x4;
typedef short s16;
typedef unsigned int u32;
typedef unsigned short u16;

#define S_LEN 2048
#define HIDN  2048
#define QKVW  3072
#define NH    32
#define NKVH  8
#define HD    64

__device__ __forceinline__ s16 f2bf(float f) {
  unsigned int u = __float_as_uint(f);
  unsigned int lsb = (u >> 16) & 1u;
  u += 0x7fffu + lsb;
  return (s16)(u >> 16);
}

__device__ __forceinline__ void gload16(const void* g, void* l) {
  __builtin_amdgcn_global_load_lds(
      (const __attribute__((address_space(1))) void*)g,
      (__attribute__((address_space(3))) void*)l, 16, 0, 0);
}

// all 5 f32->bf16 conversions in one launch; dest regions are contiguous in ws
__global__ __launch_bounds__(256) void cvt_all(const float* __restrict__ h,
                                               const float* __restrict__ wq,
                                               const float* __restrict__ wk,
                                               const float* __restrict__ wv,
                                               const float* __restrict__ wo,
                                               s16x4* __restrict__ dst) {
  int i = blockIdx.x * 256 + threadIdx.x;
  const float* src; int off;
  if (i < 1048576)      { src = h;  off = i; }
  else if (i < 2097152) { src = wq; off = i - 1048576; }
  else if (i < 2359296) { src = wk; off = i - 2097152; }
  else if (i < 2621440) { src = wv; off = i - 2359296; }
  else                  { src = wo; off = i - 2621440; }
  if (i < 3670016) {
    float4 f = reinterpret_cast<const float4*>(src)[off];
    s16x4 o;
    o.x = f2bf(f.x); o.y = f2bf(f.y); o.z = f2bf(f.z); o.w = f2bf(f.w);
    dst[i] = o;
  }
}

__device__ __forceinline__ void storeC(s16* C, size_t idx, float v)   { C[idx] = f2bf(v); }
__device__ __forceinline__ void storeC(float* C, size_t idx, float v) { C[idx] = v; }

// C[M,N] = A[M,K] * B[N,K]^T. BM=BN=128, BK=32, 4 waves (2x2 of 64x64).
// global_load_lds staging with pre-swizzled source slots (conflict-free reads).
template <typename OUT_T>
__global__ __launch_bounds__(256) void gemm_bt(const s16* __restrict__ A,
                                               const s16* __restrict__ B,
                                               OUT_T* __restrict__ C,
                                               int M, int N, int K) {
  __shared__ alignas(16) s16 As[128 * 32];
  __shared__ alignas(16) s16 Bs[128 * 32];

  const int t    = threadIdx.x;
  const int lane = t & 63;
  const int w    = t >> 6;
  const int wr   = (w >> 1) * 64;
  const int wc   = (w & 1) * 64;
  const int lr   = lane & 15;
  const int lg   = lane >> 4;
  const int bm   = blockIdx.y * 128;
  const int bn   = blockIdx.x * 128;

  const int srow  = lane >> 2;                       // row within 16-row chunk
  const int sslot = (lane & 3) ^ ((lane >> 3) & 3);  // pre-swizzled 16B slot
  const int flr   = (lr >> 1) & 3;                   // read-side slot XOR

  f32x4 acc[4][4];
#pragma unroll
  for (int m = 0; m < 4; ++m)
#pragma unroll
    for (int n = 0; n < 4; ++n)
      acc[m][n] = (f32x4){0.f, 0.f, 0.f, 0.f};

  for (int kt = 0; kt < K; kt += 32) {
#pragma unroll
    for (int p = 0; p < 2; ++p) {
      int c = w * 2 + p;  // chunks 0..7, 16 rows each
      gload16(&A[(size_t)(bm + c * 16 + srow) * K + kt + sslot * 8], (char*)As + c * 1024);
      gload16(&B[(size_t)(bn + c * 16 + srow) * K + kt + sslot * 8], (char*)Bs + c * 1024);
    }
    __syncthreads();

    bf16x8 af[4], bfr[4];
#pragma unroll
    for (int m = 0; m < 4; ++m) {
      int row = wr + m * 16 + lr;
      af[m] = *(bf16x8*)((char*)As + row * 64 + ((lg ^ flr) << 4));
    }
#pragma unroll
    for (int n = 0; n < 4; ++n) {
      int row = wc + n * 16 + lr;
      bfr[n] = *(bf16x8*)((char*)Bs + row * 64 + ((lg ^ flr) << 4));
    }

#pragma unroll
    for (int m = 0; m < 4; ++m)
#pragma unroll
      for (int n = 0; n < 4; ++n)
        acc[m][n] = __builtin_amdgcn_mfma_f32_16x16x32_bf16(af[m], bfr[n], acc[m][n], 0, 0, 0);
    __syncthreads();
  }

#pragma unroll
  for (int m = 0; m < 4; ++m)
#pragma unroll
    for (int n = 0; n < 4; ++n) {
      int row = bm + wr + m * 16 + lg * 4;
      int col = bn + wc + n * 16 + lr;
#pragma unroll
      for (int j = 0; j < 4; ++j)
        storeC(C, (size_t)(row + j) * N + col, acc[m][n][j]);
    }
}

// ---------------- flash attention (swapped-QK, in-register softmax) ----------
__device__ __forceinline__ int swz7(int row) { return (row ^ (row >> 3)) & 7; }

__global__ __launch_bounds__(256) void attn_kernel(
    const s16* __restrict__ QKV,   // [2048][3072]
    const int* __restrict__ am,    // [2048]
    s16* __restrict__ Ob) {        // [2048][2048]
  __shared__ alignas(16) char KsB[2][8192];   // K [64 kv][64 d], swizzled slots
  __shared__ alignas(16) char VsB[2][8192];   // V^T [64 d][64 kv], swizzled
  __shared__ alignas(16) char PsB[8192];      // per-wave P [16 q][64 kv], swizzled

  const int t    = threadIdx.x;
  const int lane = t & 63;
  const int w    = t >> 6;
  const int lr   = lane & 15;
  const int lg   = lane >> 4;

  const int qblk = (int)gridDim.x - 1 - (int)blockIdx.x;
  const int h    = blockIdx.y;
  const int hk   = h >> 2;
  const int q0   = qblk * 64;
  const int kbase = 2048 + hk * 64;
  const int vbase = 2560 + hk * 64;

  const int qrow = q0 + w * 16 + lr;
  bf16x8 qf0 = *(const bf16x8*)&QKV[(size_t)qrow * QKVW + h * 64 + lg * 8];
  bf16x8 qf1 = *(const bf16x8*)&QKV[(size_t)qrow * QKVW + h * 64 + 32 + lg * 8];

  float m_i = -1e30f, l_i = 0.f;
  f32x4 Oacc[4];
#pragma unroll
  for (int nd = 0; nd < 4; ++nd) Oacc[nd] = (f32x4){0.f, 0.f, 0.f, 0.f};

  const float CF = 0.18033688f;  // 0.125 * log2(e)
  const int nt = qblk + 1;

  const int krow   = lane >> 3;
  const int kslotb = lane & 7;
  const int vkv    = 2 * (t >> 3);
  const int vd8    = (t & 7) * 8;
  const int g7     = swz7(lr);
  const int psbase = w * 2048 + lr * 128;

  // ---- prologue: stage tile 0 into buffer 0 ----
  {
#pragma unroll
    for (int p = 0; p < 2; ++p) {
      int c   = w * 2 + p;
      int row = c * 8 + krow;
      int slot = kslotb ^ swz7(row);
      gload16(&QKV[(size_t)row * QKVW + kbase + slot * 8], KsB[0] + c * 1024);
    }
    bf16x8 va = *(const bf16x8*)&QKV[(size_t)vkv * QKVW + vbase + vd8];
    bf16x8 vb = *(const bf16x8*)&QKV[(size_t)(vkv + 1) * QKVW + vbase + vd8];
#pragma unroll
    for (int i = 0; i < 8; ++i) {
      int d = vd8 + i;
      u32 pk = (u32)(u16)va[i] | ((u32)(u16)vb[i] << 16);
      *(u32*)&VsB[0][(d * 128 + vkv * 2) ^ (swz7(d) << 4)] = pk;
    }
    __syncthreads();
  }

  for (int it = 0; it < nt; ++it) {
    const int cur = it & 1;
    const int kv0 = it * 64;

    // ---- async stage of next tile (issue early) ----
    bf16x8 va, vb;
    const bool pre = (it + 1 < nt);
    if (pre) {
      const int nk0 = kv0 + 64;
#pragma unroll
      for (int p = 0; p < 2; ++p) {
        int c   = w * 2 + p;
        int row = c * 8 + krow;
        int slot = kslotb ^ swz7(row);
        gload16(&QKV[(size_t)(nk0 + row) * QKVW + kbase + slot * 8], KsB[cur ^ 1] + c * 1024);
      }
      va = *(const bf16x8*)&QKV[(size_t)(nk0 + vkv) * QKVW + vbase + vd8];
      vb = *(const bf16x8*)&QKV[(size_t)(nk0 + vkv + 1) * QKVW + vbase + vd8];
    }

    // ---- S^T = K Q^T : lane holds q = lr, kv = kv0 + 16n + 4lg + j ----
    f32x4 sn[4];
#pragma unroll
    for (int n = 0; n < 4; ++n) {
      int row = n * 16 + lr;
      int sw  = swz7(row) << 4;
      bf16x8 k0 = *(bf16x8*)&KsB[cur][(row * 128 + lg * 16) ^ sw];
      bf16x8 k1 = *(bf16x8*)&KsB[cur][(row * 128 + 64 + lg * 16) ^ sw];
      f32x4 z = (f32x4){0.f, 0.f, 0.f, 0.f};
      z = __builtin_amdgcn_mfma_f32_16x16x32_bf16(k0, qf0, z, 0, 0, 0);
      sn[n] = __builtin_amdgcn_mfma_f32_16x16x32_bf16(k1, qf1, z, 0, 0, 0);
    }

    // ---- mask + scale ----
    float pv[16];
    int a = am[kv0 + lane];
    unsigned long long m64 = __ballot(a != 0);
    bool interior = (kv0 + 63 <= q0 + 16 * w) && (m64 == ~0ull);
    if (interior) {
#pragma unroll
      for (int n = 0; n < 4; ++n)
#pragma unroll
        for (int j = 0; j < 4; ++j) pv[n * 4 + j] = sn[n][j] * CF;
    } else {
      const int qg = q0 + 16 * w + lr;
#pragma unroll
      for (int n = 0; n < 4; ++n) {
        u32 un = (u32)(m64 >> (16 * n + 4 * lg)) & 0xFu;
#pragma unroll
        for (int j = 0; j < 4; ++j) {
          int kvg = kv0 + 16 * n + 4 * lg + j;
          bool ok = (kvg <= qg) && ((un >> j) & 1u);
          pv[n * 4 + j] = ok ? sn[n][j] * CF : -INFINITY;
        }
      }
    }

    // ---- in-register online softmax (lane owns q-row lr's 16 kv values) ----
    float lmax = pv[0];
#pragma unroll
    for (int i = 1; i < 16; ++i) lmax = fmaxf(lmax, pv[i]);
    lmax = fmaxf(lmax, __shfl_xor(lmax, 16));
    lmax = fmaxf(lmax, __shfl_xor(lmax, 32));

    float nm = fmaxf(m_i, lmax);
    float al = __builtin_amdgcn_exp2f(m_i - nm);
    m_i = nm;

    float lsum = 0.f;
#pragma unroll
    for (int n = 0; n < 4; ++n) {
      s16x4 pk;
#pragma unroll
      for (int j = 0; j < 4; ++j) {
        float p = __builtin_amdgcn_exp2f(pv[n * 4 + j] - nm);
        lsum += p;
        pk[j] = f2bf(p);
      }
      *(s16x4*)&PsB[psbase + ((((2 * n + (lg >> 1)) ^ g7) << 4) | ((lg & 1) * 8))] = pk;
    }
    lsum += __shfl_xor(lsum, 16);
    lsum += __shfl_xor(lsum, 32);
    l_i = l_i * al + lsum;

    // broadcast al to the C-layout rows (q = 4*lg + j), rescale O
    float albc[4];
#pragma unroll
    for (int j = 0; j < 4; ++j) albc[j] = __shfl(al, 20 * lg + j);
#pragma unroll
    for (int nd = 0; nd < 4; ++nd)
#pragma unroll
      for (int j = 0; j < 4; ++j) Oacc[nd][j] *= albc[j];

    // ---- O += P V ----
    bf16x8 pf0 = *(bf16x8*)&PsB[psbase + ((lg ^ g7) << 4)];
    bf16x8 pf1 = *(bf16x8*)&PsB[psbase + (((4 + lg) ^ g7) << 4)];
#pragma unroll
    for (int nd = 0; nd < 4; ++nd) {
      int d  = nd * 16 + lr;
      int sw = swz7(d) << 4;
      bf16x8 v0 = *(bf16x8*)&VsB[cur][(d * 128 + lg * 16) ^ sw];
      bf16x8 v1 = *(bf16x8*)&VsB[cur][(d * 128 + 64 + lg * 16) ^ sw];
      Oacc[nd] = __builtin_amdgcn_mfma_f32_16x16x32_bf16(pf0, v0, Oacc[nd], 0, 0, 0);
      Oacc[nd] = __builtin_amdgcn_mfma_f32_16x16x32_bf16(pf1, v1, Oacc[nd], 0, 0, 0);
    }

    // ---- late half of async stage: pack + write V^T(next) ----
    if (pre) {
#pragma unroll
      for (int i = 0; i < 8; ++i) {
        int d = vd8 + i;
        u32 pk = (u32)(u16)va[i] | ((u32)(u16)vb[i] << 16);
        *(u32*)&VsB[cur ^ 1][(d * 128 + vkv * 2) ^ (swz7(d) << 4)] = pk;
      }
    }
    __syncthreads();  // drains K gload vmcnt + V ds_writes for all waves
  }

  // epilogue
  float linv[4];
#pragma unroll
  for (int j = 0; j < 4; ++j) linv[j] = 1.0f / __shfl(l_i, 20 * lg + j);
#pragma unroll
  for (int nd = 0; nd < 4; ++nd)
#pragma unroll
    for (int j = 0; j < 4; ++j) {
      int row = q0 + 16 * w + 4 * lg + j;
      int col = h * 64 + nd * 16 + lr;
      Ob[(size_t)row * HIDN + col] = f2bf(Oacc[nd][j] * linv[j]);
    }
}

extern "C" void kernel_launch(void* const* d_in, const int* in_sizes, int n_in,
                              void* d_out, int out_size, void* d_ws, size_t ws_size,
                              hipStream_t stream) {
  const float* hidden = (const float*)d_in[0];
  const int*   am     = (const int*)d_in[1];
  const float* Wq     = (const float*)d_in[2];
  const float* Wk     = (const float*)d_in[3];
  const float* Wv     = (const float*)d_in[4];
  const float* Wo     = (const float*)d_in[5];
  float* out = (float*)d_out;

  s16* hb    = (s16*)d_ws;          // hidden  [2048][2048]
  s16* wqkvb = hb    + 4194304;     // W_qkv   [3072][2048]
  s16* wob   = wqkvb + 6291456;     // Wo      [2048][2048]
  s16* QKVb  = wob   + 4194304;     // QKV     [2048][3072]
  s16* Ab    = QKVb  + 6291456;     // attnout [2048][2048]

  cvt_all<<<14336, 256, 0, stream>>>(hidden, Wq, Wk, Wv, Wo, (s16x4*)d_ws);

  gemm_bt<s16><<<dim3(24, 16), 256, 0, stream>>>(hb, wqkvb, QKVb, 2048, 3072, 2048);

  attn_kernel<<<dim3(32, 32), 256, 0, stream>>>(QKVb, am, Ab);

  gemm_bt<float><<<dim3(16, 16), 256, 0, stream>>>(Ab, wob, out, 2048, 2048, 2048);
}

// Round 5
// 168.748 us; speedup vs baseline: 2.4874x; 1.2270x over previous
//
#include <hip/hip_runtime.h>
#include <hip/hip_bf16.h>
#include <math.h>

typedef __attribute__((ext_vector_type(4))) float f32x4;
typedef __attribute__((ext_vector_type(8))) short bf16x8;
typedef __attribute__((ext_vector_type(4))) short s16x4;
typedef short s16;
typedef unsigned int u32;
typedef unsigned short u16;

#define S_LEN 2048
#define HIDN  2048
#define QKVW  3072
#define NH    32
#define NKVH  8
#define HD    64

__device__ __forceinline__ s16 f2bf(float f) {
  unsigned int u = __float_as_uint(f);
  unsigned int lsb = (u >> 16) & 1u;
  u += 0x7fffu + lsb;
  return (s16)(u >> 16);
}

__device__ __forceinline__ void gload16(const void* g, void* l) {
  __builtin_amdgcn_global_load_lds(
      (const __attribute__((address_space(1))) void*)g,
      (__attribute__((address_space(3))) void*)l, 16, 0, 0);
}

// all 5 f32->bf16 conversions in one launch; dest regions are contiguous in ws
__global__ __launch_bounds__(256) void cvt_all(const float* __restrict__ h,
                                               const float* __restrict__ wq,
                                               const float* __restrict__ wk,
                                               const float* __restrict__ wv,
                                               const float* __restrict__ wo,
                                               s16x4* __restrict__ dst) {
  int i = blockIdx.x * 256 + threadIdx.x;
  const float* src; int off;
  if (i < 1048576)      { src = h;  off = i; }
  else if (i < 2097152) { src = wq; off = i - 1048576; }
  else if (i < 2359296) { src = wk; off = i - 2097152; }
  else if (i < 2621440) { src = wv; off = i - 2359296; }
  else                  { src = wo; off = i - 2621440; }
  if (i < 3670016) {
    float4 f = reinterpret_cast<const float4*>(src)[off];
    s16x4 o;
    o.x = f2bf(f.x); o.y = f2bf(f.y); o.z = f2bf(f.z); o.w = f2bf(f.w);
    dst[i] = o;
  }
}

__device__ __forceinline__ void storeC(s16* C, size_t idx, float v)   { C[idx] = f2bf(v); }
__device__ __forceinline__ void storeC(float* C, size_t idx, float v) { C[idx] = v; }

// C[M,N] = A[M,K] * B[N,K]^T. BM=BN=128, BK=32, 4 waves (2x2 of 64x64).
template <typename OUT_T>
__global__ __launch_bounds__(256) void gemm_bt(const s16* __restrict__ A,
                                               const s16* __restrict__ B,
                                               OUT_T* __restrict__ C,
                                               int M, int N, int K) {
  __shared__ alignas(16) s16 As[128 * 32];
  __shared__ alignas(16) s16 Bs[128 * 32];

  const int t    = threadIdx.x;
  const int lane = t & 63;
  const int w    = t >> 6;
  const int wr   = (w >> 1) * 64;
  const int wc   = (w & 1) * 64;
  const int lr   = lane & 15;
  const int lg   = lane >> 4;
  const int bm   = blockIdx.y * 128;
  const int bn   = blockIdx.x * 128;

  const int srow  = lane >> 2;
  const int sslot = (lane & 3) ^ ((lane >> 3) & 3);
  const int flr   = (lr >> 1) & 3;

  f32x4 acc[4][4];
#pragma unroll
  for (int m = 0; m < 4; ++m)
#pragma unroll
    for (int n = 0; n < 4; ++n)
      acc[m][n] = (f32x4){0.f, 0.f, 0.f, 0.f};

  for (int kt = 0; kt < K; kt += 32) {
#pragma unroll
    for (int p = 0; p < 2; ++p) {
      int c = w * 2 + p;
      gload16(&A[(size_t)(bm + c * 16 + srow) * K + kt + sslot * 8], (char*)As + c * 1024);
      gload16(&B[(size_t)(bn + c * 16 + srow) * K + kt + sslot * 8], (char*)Bs + c * 1024);
    }
    __syncthreads();

    bf16x8 af[4], bfr[4];
#pragma unroll
    for (int m = 0; m < 4; ++m) {
      int row = wr + m * 16 + lr;
      af[m] = *(bf16x8*)((char*)As + row * 64 + ((lg ^ flr) << 4));
    }
#pragma unroll
    for (int n = 0; n < 4; ++n) {
      int row = wc + n * 16 + lr;
      bfr[n] = *(bf16x8*)((char*)Bs + row * 64 + ((lg ^ flr) << 4));
    }

#pragma unroll
    for (int m = 0; m < 4; ++m)
#pragma unroll
      for (int n = 0; n < 4; ++n)
        acc[m][n] = __builtin_amdgcn_mfma_f32_16x16x32_bf16(af[m], bfr[n], acc[m][n], 0, 0, 0);
    __syncthreads();
  }

#pragma unroll
  for (int m = 0; m < 4; ++m)
#pragma unroll
    for (int n = 0; n < 4; ++n) {
      int row = bm + wr + m * 16 + lg * 4;
      int col = bn + wc + n * 16 + lr;
#pragma unroll
      for (int j = 0; j < 4; ++j)
        storeC(C, (size_t)(row + j) * N + col, acc[m][n][j]);
    }
}

// ---------------- flash attention: GQA-fused, pair-balanced, O^T accum ------
// Block = (kv-head hk, pair p): q-tiles qtA=p, qtB=127-p (16 rows each),
// 4 waves = 4 q-heads of the group sharing staged K/V. 33 KV-tiles/block.
__device__ __forceinline__ int swz7(int row) { return (row ^ (row >> 3)) & 7; }

__global__ __launch_bounds__(256) void attn_kernel(
    const s16* __restrict__ QKV,   // [2048][3072]
    const int* __restrict__ am,    // [2048]
    s16* __restrict__ Ob) {        // [2048][2048]
  __shared__ alignas(16) char KsB[2][8192];   // K [64 kv][64 d], swizzled slots
  __shared__ alignas(16) char VsB[2][8192];   // V^T [64 d][64 kv], swizzled
  __shared__ alignas(16) char PsB[8192];      // per-wave P [16 q][64 kv], swizzled

  const int t    = threadIdx.x;
  const int lane = t & 63;
  const int w    = t >> 6;
  const int lr   = lane & 15;
  const int lg   = lane >> 4;

  const int hk = blockIdx.y;
  const int p  = blockIdx.x;
  const int h  = hk * 4 + w;          // this wave's query head
  const int kbase = 2048 + hk * 64;
  const int vbase = 2560 + hk * 64;

  const float CF = 0.18033688f;  // 0.125 * log2(e)

  const int krow   = lane >> 3;
  const int kslotb = lane & 7;
  const int vkv    = 2 * (t >> 3);
  const int vd8    = (t & 7) * 8;
  const int g7     = swz7(lr);
  const int psbase = w * 2048 + lr * 128;

  int buf = 0;

  // ---- prologue: stage tile kv0=0 into buffer 0 ----
  {
#pragma unroll
    for (int pp = 0; pp < 2; ++pp) {
      int c   = w * 2 + pp;
      int row = c * 8 + krow;
      int slot = kslotb ^ swz7(row);
      gload16(&QKV[(size_t)row * QKVW + kbase + slot * 8], KsB[0] + c * 1024);
    }
    bf16x8 va = *(const bf16x8*)&QKV[(size_t)vkv * QKVW + vbase + vd8];
    bf16x8 vb = *(const bf16x8*)&QKV[(size_t)(vkv + 1) * QKVW + vbase + vd8];
#pragma unroll
    for (int i = 0; i < 8; ++i) {
      int d = vd8 + i;
      u32 pk = (u32)(u16)va[i] | ((u32)(u16)vb[i] << 16);
      *(u32*)&VsB[0][(d * 128 + vkv * 2) ^ (swz7(d) << 4)] = pk;
    }
  }
  int acur = am[lane];
  __syncthreads();

  for (int phase = 0; phase < 2; ++phase) {
    const int qt   = phase ? 127 - p : p;
    const int nt   = (qt >> 2) + 1;
    const int qrow = qt * 16 + lr;

    bf16x8 qf0 = *(const bf16x8*)&QKV[(size_t)qrow * QKVW + h * 64 + lg * 8];
    bf16x8 qf1 = *(const bf16x8*)&QKV[(size_t)qrow * QKVW + h * 64 + 32 + lg * 8];

    float m_i = -1e30f, l_i = 0.f;
    f32x4 Oacc[4];
#pragma unroll
    for (int nd = 0; nd < 4; ++nd) Oacc[nd] = (f32x4){0.f, 0.f, 0.f, 0.f};

    for (int it = 0; it < nt; ++it) {
      const int cur = buf;
      const int kv0 = it * 64;
      const int nk0 = (it + 1 < nt) ? kv0 + 64 : (phase == 0 ? 0 : -1);

      // ---- async stage of next tile (issue early) ----
      bf16x8 va, vb;
      int anext = 0;
      if (nk0 >= 0) {
#pragma unroll
        for (int pp = 0; pp < 2; ++pp) {
          int c   = w * 2 + pp;
          int row = c * 8 + krow;
          int slot = kslotb ^ swz7(row);
          gload16(&QKV[(size_t)(nk0 + row) * QKVW + kbase + slot * 8], KsB[cur ^ 1] + c * 1024);
        }
        va = *(const bf16x8*)&QKV[(size_t)(nk0 + vkv) * QKVW + vbase + vd8];
        vb = *(const bf16x8*)&QKV[(size_t)(nk0 + vkv + 1) * QKVW + vbase + vd8];
        anext = am[nk0 + lane];
      }

      // ---- S^T = K Q^T : lane holds q = lr, kv = kv0 + 16n + 4lg + j ----
      f32x4 sn[4];
      __builtin_amdgcn_s_setprio(1);
#pragma unroll
      for (int n = 0; n < 4; ++n) {
        int row = n * 16 + lr;
        int sw  = swz7(row) << 4;
        bf16x8 k0 = *(bf16x8*)&KsB[cur][(row * 128 + lg * 16) ^ sw];
        bf16x8 k1 = *(bf16x8*)&KsB[cur][(row * 128 + 64 + lg * 16) ^ sw];
        f32x4 z = (f32x4){0.f, 0.f, 0.f, 0.f};
        z = __builtin_amdgcn_mfma_f32_16x16x32_bf16(k0, qf0, z, 0, 0, 0);
        sn[n] = __builtin_amdgcn_mfma_f32_16x16x32_bf16(k1, qf1, z, 0, 0, 0);
      }
      __builtin_amdgcn_s_setprio(0);

      // ---- mask + scale ----
      float pvv[16];
      unsigned long long m64 = __ballot(acur != 0);
      bool interior = (kv0 + 63 <= qt * 16) && (m64 == ~0ull);
      if (interior) {
#pragma unroll
        for (int n = 0; n < 4; ++n)
#pragma unroll
          for (int j = 0; j < 4; ++j) pvv[n * 4 + j] = sn[n][j] * CF;
      } else {
#pragma unroll
        for (int n = 0; n < 4; ++n) {
          u32 un = (u32)(m64 >> (16 * n + 4 * lg)) & 0xFu;
#pragma unroll
          for (int j = 0; j < 4; ++j) {
            int kvg = kv0 + 16 * n + 4 * lg + j;
            bool ok = (kvg <= qrow) && ((un >> j) & 1u);
            pvv[n * 4 + j] = ok ? sn[n][j] * CF : -INFINITY;
          }
        }
      }

      // ---- in-register online softmax (lane-local q row = lr) ----
      float lmax = pvv[0];
#pragma unroll
      for (int i = 1; i < 16; ++i) lmax = fmaxf(lmax, pvv[i]);
      lmax = fmaxf(lmax, __shfl_xor(lmax, 16));
      lmax = fmaxf(lmax, __shfl_xor(lmax, 32));

      float nm = fmaxf(m_i, lmax);
      float al = __builtin_amdgcn_exp2f(m_i - nm);
      m_i = nm;

      float lsum = 0.f;
#pragma unroll
      for (int n = 0; n < 4; ++n) {
        s16x4 pk;
#pragma unroll
        for (int j = 0; j < 4; ++j) {
          float pe = __builtin_amdgcn_exp2f(pvv[n * 4 + j] - nm);
          lsum += pe;
          pk[j] = f2bf(pe);
        }
        *(s16x4*)&PsB[psbase + ((((2 * n + (lg >> 1)) ^ g7) << 4) | ((lg & 1) * 8))] = pk;
      }
      lsum += __shfl_xor(lsum, 16);
      lsum += __shfl_xor(lsum, 32);
      l_i = l_i * al + lsum;

      // lane-local rescale of O^T (q = lr for every element)
#pragma unroll
      for (int nd = 0; nd < 4; ++nd)
#pragma unroll
        for (int j = 0; j < 4; ++j) Oacc[nd][j] *= al;

      // ---- O^T += V^T P^T (swapped operands: q stays lane-local) ----
      bf16x8 pf0 = *(bf16x8*)&PsB[psbase + ((lg ^ g7) << 4)];
      bf16x8 pf1 = *(bf16x8*)&PsB[psbase + (((4 + lg) ^ g7) << 4)];
      __builtin_amdgcn_s_setprio(1);
#pragma unroll
      for (int nd = 0; nd < 4; ++nd) {
        int d  = nd * 16 + lr;
        int sw = swz7(d) << 4;
        bf16x8 v0 = *(bf16x8*)&VsB[cur][(d * 128 + lg * 16) ^ sw];
        bf16x8 v1 = *(bf16x8*)&VsB[cur][(d * 128 + 64 + lg * 16) ^ sw];
        Oacc[nd] = __builtin_amdgcn_mfma_f32_16x16x32_bf16(v0, pf0, Oacc[nd], 0, 0, 0);
        Oacc[nd] = __builtin_amdgcn_mfma_f32_16x16x32_bf16(v1, pf1, Oacc[nd], 0, 0, 0);
      }
      __builtin_amdgcn_s_setprio(0);

      // ---- late half of async stage: pack + write V^T(next) ----
      if (nk0 >= 0) {
#pragma unroll
        for (int i = 0; i < 8; ++i) {
          int d = vd8 + i;
          u32 pk = (u32)(u16)va[i] | ((u32)(u16)vb[i] << 16);
          *(u32*)&VsB[cur ^ 1][(d * 128 + vkv * 2) ^ (swz7(d) << 4)] = pk;
        }
        acur = anext;
      }
      __syncthreads();
      buf = cur ^ 1;
    }

    // ---- epilogue: O^T -> Ob, lane-local divide, 8B packed stores ----
    float linv = 1.0f / l_i;
#pragma unroll
    for (int nd = 0; nd < 4; ++nd) {
      s16x4 o;
#pragma unroll
      for (int j = 0; j < 4; ++j) o[j] = f2bf(Oacc[nd][j] * linv);
      *(s16x4*)&Ob[(size_t)qrow * HIDN + h * 64 + nd * 16 + lg * 4] = o;
    }
  }
}

extern "C" void kernel_launch(void* const* d_in, const int* in_sizes, int n_in,
                              void* d_out, int out_size, void* d_ws, size_t ws_size,
                              hipStream_t stream) {
  const float* hidden = (const float*)d_in[0];
  const int*   am     = (const int*)d_in[1];
  const float* Wq     = (const float*)d_in[2];
  const float* Wk     = (const float*)d_in[3];
  const float* Wv     = (const float*)d_in[4];
  const float* Wo     = (const float*)d_in[5];
  float* out = (float*)d_out;

  s16* hb    = (s16*)d_ws;          // hidden  [2048][2048]
  s16* wqkvb = hb    + 4194304;     // W_qkv   [3072][2048]
  s16* wob   = wqkvb + 6291456;     // Wo      [2048][2048]
  s16* QKVb  = wob   + 4194304;     // QKV     [2048][3072]
  s16* Ab    = QKVb  + 6291456;     // attnout [2048][2048]

  cvt_all<<<14336, 256, 0, stream>>>(hidden, Wq, Wk, Wv, Wo, (s16x4*)d_ws);

  gemm_bt<s16><<<dim3(24, 16), 256, 0, stream>>>(hb, wqkvb, QKVb, 2048, 3072, 2048);

  attn_kernel<<<dim3(64, 8), 256, 0, stream>>>(QKVb, am, Ab);

  gemm_bt<float><<<dim3(16, 16), 256, 0, stream>>>(Ab, wob, out, 2048, 2048, 2048);
}